// Round 5
// baseline (1199.400 us; speedup 1.0000x reference)
//
#include <hip/hip_runtime.h>
#include <stdint.h>

#define Hd 1024
#define Bd 32
#define Td 64
#define Vd 32000
#define TB (Td*Bd)            // 2048
#define G3H 3072
#define NB 64                 // GRU blocks (block 0..63)
#define NPOOL 192             // logits-GEMM pool blocks (block 64..255)
#define JC 16                 // h-columns per GRU block
#define NTILE 250             // 32000 / 128
static const size_t BTV = (size_t)Bd * Td * Vd;   // 65,536,000

typedef unsigned short u16;
typedef __attribute__((ext_vector_type(8))) short bf16x8;
typedef __attribute__((ext_vector_type(4))) float f32x4;
typedef __attribute__((ext_vector_type(4))) unsigned int u32x4;

typedef __attribute__((address_space(3))) void lds_void;
typedef __attribute__((address_space(1))) const void gbl_void;

__device__ __forceinline__ void async_ld16(const void* g, void* l) {
    __builtin_amdgcn_global_load_lds((gbl_void*)g, (lds_void*)l, 16, 0, 0);
}

__device__ __forceinline__ u16 f2bf(float f) {
    union { float f; uint32_t u; } v; v.f = f;
    uint32_t u = v.u;
    return (u16)((u + 0x7fffu + ((u >> 16) & 1u)) >> 16);
}

// PROVEN primitives: sc0 sc1 cache-bypassing load/store, coherent for all
// blocks at the coherence point (LLC-served per round-1 FETCH_SIZE evidence).
__device__ __forceinline__ u32x4 gload_b128_sc(const u16* p) {
    u32x4 r;
    asm volatile("global_load_dwordx4 %0, %1, off sc0 sc1"
                 : "=v"(r) : "v"(p) : "memory");
    return r;
}
__device__ __forceinline__ void gstore_b32_sc(u16* p, unsigned int v) {
    asm volatile("global_store_dword %0, %1, off sc0 sc1"
                 :: "v"(p), "v"(v) : "memory");
}
__device__ __forceinline__ void gstore_u32_sc(unsigned int* p, unsigned int v) {
    asm volatile("global_store_dword %0, %1, off sc0 sc1"
                 :: "v"(p), "v"(v) : "memory");
}
// NON-TEMPORAL store: no LLC allocation. Logits are written once and only
// re-read by the NEXT kernel -> caching them evicts w_out (round-4 thrash).
__device__ __forceinline__ void gstore_f32_nt(float* p, float v) {
    asm volatile("global_store_dword %0, %1, off nt"
                 :: "v"(p), "v"(v) : "memory");
}

__device__ __forceinline__ float fsigmoid(float x) {
    return __builtin_amdgcn_rcpf(1.f + __expf(-x));
}
__device__ __forceinline__ float ftanh(float x) {
    return 1.f - 2.f * __builtin_amdgcn_rcpf(1.f + __expf(2.f * x));
}

// ---------------- fp32 -> bf16 convert ----------------
__global__ void k_conv_bf16(const float* __restrict__ src, u16* __restrict__ dst, int n4) {
    int i = blockIdx.x * blockDim.x + threadIdx.x;
    if (i >= n4) return;
    float4 f = ((const float4*)src)[i];
    ushort4 o;
    o.x = f2bf(f.x); o.y = f2bf(f.y); o.z = f2bf(f.z); o.w = f2bf(f.w);
    ((ushort4*)dst)[i] = o;
}

// ---------------- embedding gather + relu + bf16 ----------------
__global__ void k_embed(const float* __restrict__ emb, const int* __restrict__ tgt,
                        u16* __restrict__ Xb) {
    int r = blockIdx.x;            // r = t*32 + b
    int t = r >> 5, b = r & 31;
    int tok = (t == 0) ? 1 : tgt[b * Td + (t - 1)];
    const float4* srow = (const float4*)(emb + (size_t)tok * Hd);
    int k = threadIdx.x;
    float4 f = srow[k];
    ushort4 o;
    o.x = f2bf(fmaxf(f.x, 0.f)); o.y = f2bf(fmaxf(f.y, 0.f));
    o.z = f2bf(fmaxf(f.z, 0.f)); o.w = f2bf(fmaxf(f.w, 0.f));
    ((ushort4*)(Xb + (size_t)r * Hd))[k] = o;
}

// ---------------- h init: bf16 copy + barrier-flag zero ----------------
__global__ void k_init_h(const float* __restrict__ eh, u16* __restrict__ hb,
                         unsigned int* __restrict__ cnt) {
    if (blockIdx.x == 0 && threadIdx.x < NB) cnt[threadIdx.x] = 0u;
    int i = blockIdx.x * blockDim.x + threadIdx.x;   // 8192 float4s
    float4 f = ((const float4*)eh)[i];
    ushort4 o;
    o.x = f2bf(f.x); o.y = f2bf(f.y); o.z = f2bf(f.z); o.w = f2bf(f.w);
    ((ushort4*)hb)[i] = o;
}

// ---------------- 128x128 bf16 MFMA GEMM: C = A @ Bm^T + bias (gi only) ---
template<int MODE, int SWAP>
__global__ __launch_bounds__(256, 2)
void k_gemm128(const u16* __restrict__ A, const u16* __restrict__ Bm,
               const float* __restrict__ bias, float* __restrict__ C,
               int N, int K)
{
    __shared__ alignas(16) u16 As[128 * 32];
    __shared__ alignas(16) u16 Bs[128 * 32];
    const int tid  = threadIdx.x;
    const int wave = tid >> 6;
    const int lane = tid & 63;
    const int l16  = lane & 15;
    const int q    = lane >> 4;
    const int wm   = (wave & 1) << 6;
    const int wn   = (wave >> 1) << 6;
    const int tm   = (SWAP ? blockIdx.x : blockIdx.y) << 7;
    const int tn   = (SWAP ? blockIdx.y : blockIdx.x) << 7;

    f32x4 acc[4][4];
#pragma unroll
    for (int i = 0; i < 4; ++i)
#pragma unroll
        for (int j = 0; j < 4; ++j) { f32x4 z = {0.f,0.f,0.f,0.f}; acc[i][j] = z; }

    const int c0 = wave * 2, c1 = wave * 2 + 1;
    const int cr = lane >> 2;
    const int kg = lane & 3;
    const u16* gA0 = A + (size_t)(tm + c0*16 + cr) * K + kg*8;
    const u16* gA1 = A + (size_t)(tm + c1*16 + cr) * K + kg*8;
    const u16* gB0 = Bm + (size_t)(tn + c0*16 + cr) * K + kg*8;
    const u16* gB1 = Bm + (size_t)(tn + c1*16 + cr) * K + kg*8;
    u16* lA0 = &As[c0*512 + lane*8];
    u16* lA1 = &As[c1*512 + lane*8];
    u16* lB0 = &Bs[c0*512 + lane*8];
    u16* lB1 = &Bs[c1*512 + lane*8];

    for (int k0 = 0; k0 < K; k0 += 32) {
        async_ld16(gA0 + k0, lA0);
        async_ld16(gA1 + k0, lA1);
        async_ld16(gB0 + k0, lB0);
        async_ld16(gB1 + k0, lB1);
        __syncthreads();
        bf16x8 af[4], bfr[4];
#pragma unroll
        for (int i = 0; i < 4; ++i)
            af[i] = *(const bf16x8*)&As[(wm + i*16 + l16) * 32 + q*8];
#pragma unroll
        for (int j = 0; j < 4; ++j)
            bfr[j] = *(const bf16x8*)&Bs[(wn + j*16 + l16) * 32 + q*8];
#pragma unroll
        for (int i = 0; i < 4; ++i)
#pragma unroll
            for (int j = 0; j < 4; ++j)
                acc[i][j] = __builtin_amdgcn_mfma_f32_16x16x32_bf16(af[i], bfr[j], acc[i][j], 0, 0, 0);
        __syncthreads();
    }

#pragma unroll
    for (int i = 0; i < 4; ++i) {
        const int mbase = tm + wm + i*16 + q*4;
#pragma unroll
        for (int j = 0; j < 4; ++j) {
            const int n = tn + wn + j*16 + l16;
            const float bv = bias[n];
#pragma unroll
            for (int r = 0; r < 4; ++r) {
                const int m = mbase + r;
                const float v = acc[i][j][r] + bv;
                if (MODE == 0) {
                    C[(size_t)m * N + n] = v;
                } else {
                    const int tt = m >> 5, bb = m & 31;
                    C[(size_t)((bb << 6) + tt) * Vd + n] = v;
                }
            }
        }
    }
}

// ---------------- fused persistent: GRU recurrence + streamed logits GEMM --
// 256 blocks x 256 threads, 1 block/CU -> all co-resident.
// Blocks 0..63:  GRU. Blocks 64..255: flag-gated logits pool.
// Round-5 change: pool epilogue stores are NON-TEMPORAL -> the 262MB logits
// stream no longer write-allocates in the LLC, so w_out (65.5MB bf16) stays
// LLC-resident across all 16 groups and B staging never touches HBM.
__global__ __launch_bounds__(256, 1)
void k_gru_logits(const float* __restrict__ gi,
                  const float* __restrict__ enc_h,
                  const u16* __restrict__ w_hhb,
                  const float* __restrict__ b_hh,
                  u16* __restrict__ hbA, u16* __restrict__ hbB,
                  u16* __restrict__ hsb, float* __restrict__ hlast,
                  unsigned int* __restrict__ cnt,
                  const u16* __restrict__ w_outb,
                  const float* __restrict__ b_out,
                  float* __restrict__ out)
{
    __shared__ alignas(16) unsigned char SM[111360];
    const int tid  = threadIdx.x;
    const int wave = tid >> 6, lane = tid & 63;
    const int l16  = lane & 15, q = lane >> 4;

    if (blockIdx.x < NB) {
        // ================= GRU role =================
        u16* Ws = (u16*)SM;                                  // 48*1024 u16 = 96KB
        typedef float ghs_t[3][32][17];
        ghs_t* ghs = (ghs_t*)(SM + 98304);                   // [2][3][32][17] f32
        const int j0 = blockIdx.x * JC;

        for (int idx = tid; idx < 48 * 128; idx += 256) {
            int gr = idx >> 7;
            int c  = idx & 127;
            const u16* src = w_hhb + (size_t)((gr >> 4) * Hd + j0 + (gr & 15)) * Hd + c * 8;
            *(bf16x8*)&Ws[(size_t)(c * 48 + gr) * 8] = *(const bf16x8*)src;
        }

        const int b  = tid >> 3;
        const int jp = (tid & 7) * 2;
        float h0 = enc_h[b * Hd + j0 + jp];
        float h1 = enc_h[b * Hd + j0 + jp + 1];
        const float br0 = b_hh[j0 + jp],           br1 = b_hh[j0 + jp + 1];
        const float bz0 = b_hh[Hd + j0 + jp],      bz1 = b_hh[Hd + j0 + jp + 1];
        const float bn0 = b_hh[2*Hd + j0 + jp],    bn1 = b_hh[2*Hd + j0 + jp + 1];

        const int mh = wave & 1, kh = wave >> 1;

        float gr0, gr1, gz0, gz1, gn0, gn1;
        {
            const float* gir = gi + (size_t)b * G3H;
            gr0 = gir[j0 + jp];        gr1 = gir[j0 + jp + 1];
            gz0 = gir[Hd + j0 + jp];   gz1 = gir[Hd + j0 + jp + 1];
            gn0 = gir[2*Hd + j0 + jp]; gn1 = gir[2*Hd + j0 + jp + 1];
        }

        __syncthreads();   // Ws ready

        for (int t = 0; t < Td; ++t) {
            const u16* hb_in  = (t & 1) ? hbB : hbA;
            u16*       hb_out = (t & 1) ? hbA : hbB;
            const int row = t * 32 + b;

            const u16* ap = hb_in + (size_t)(mh*16 + l16) * Hd + kh*512 + q*8;
            u32x4 areg[16];
#pragma unroll
            for (int it = 0; it < 16; ++it)
                areg[it] = gload_b128_sc(ap + it*32);

            asm volatile("s_waitcnt vmcnt(0)" ::: "memory");

            f32x4 acc0 = {0.f,0.f,0.f,0.f}, acc1 = acc0, acc2 = acc0;
#pragma unroll
            for (int it = 0; it < 16; ++it) {
                bf16x8 a = __builtin_bit_cast(bf16x8, areg[it]);
                const int kgrp = kh*64 + it*4 + q;
                const u16* wp = &Ws[(size_t)(kgrp * 48 + l16) * 8];
                bf16x8 w0 = *(const bf16x8*)(wp);
                bf16x8 w1 = *(const bf16x8*)(wp + 16*8);
                bf16x8 w2 = *(const bf16x8*)(wp + 32*8);
                acc0 = __builtin_amdgcn_mfma_f32_16x16x32_bf16(a, w0, acc0, 0, 0, 0);
                acc1 = __builtin_amdgcn_mfma_f32_16x16x32_bf16(a, w1, acc1, 0, 0, 0);
                acc2 = __builtin_amdgcn_mfma_f32_16x16x32_bf16(a, w2, acc2, 0, 0, 0);
            }
#pragma unroll
            for (int r = 0; r < 4; ++r) {
                const int bb = mh*16 + q*4 + r;
                ghs[kh][0][bb][l16] = acc0[r];
                ghs[kh][1][bb][l16] = acc1[r];
                ghs[kh][2][bb][l16] = acc2[r];
            }
            __syncthreads();

            {
                const float hr0 = ghs[0][0][b][jp]   + ghs[1][0][b][jp]   + br0;
                const float hr1 = ghs[0][0][b][jp+1] + ghs[1][0][b][jp+1] + br1;
                const float hz0 = ghs[0][1][b][jp]   + ghs[1][1][b][jp]   + bz0;
                const float hz1 = ghs[0][1][b][jp+1] + ghs[1][1][b][jp+1] + bz1;
                const float hn0 = ghs[0][2][b][jp]   + ghs[1][2][b][jp]   + bn0;
                const float hn1 = ghs[0][2][b][jp+1] + ghs[1][2][b][jp+1] + bn1;
                const float rg0 = fsigmoid(gr0 + hr0);
                const float rg1 = fsigmoid(gr1 + hr1);
                const float zg0 = fsigmoid(gz0 + hz0);
                const float zg1 = fsigmoid(gz1 + hz1);
                const float ng0 = ftanh(gn0 + rg0 * hn0);
                const float ng1 = ftanh(gn1 + rg1 * hn1);
                h0 = (1.f - zg0) * ng0 + zg0 * h0;
                h1 = (1.f - zg1) * ng1 + zg1 * h1;
                ushort2 pv; pv.x = f2bf(h0); pv.y = f2bf(h1);
                const unsigned int pw = (unsigned int)pv.x | ((unsigned int)pv.y << 16);
                gstore_b32_sc(&hb_out[b * Hd + j0 + jp], pw);
                gstore_b32_sc(&hsb[(size_t)row * Hd + j0 + jp], pw);   // sc: pool-visible
                if (t == Td - 1) {
                    hlast[b * Hd + j0 + jp]     = h0;
                    hlast[b * Hd + j0 + jp + 1] = h1;
                }
            }

            __syncthreads();   // drains sc stores (h + hsb) to the LLC
            if (tid == 0)
                gstore_u32_sc(&cnt[blockIdx.x], (unsigned)(t + 1));  // incl. t=63 -> 64

            if (t < Td - 1) {
                {
                    const float* gir = gi + (size_t)((t + 1) * 32 + b) * G3H;
                    gr0 = gir[j0 + jp];        gr1 = gir[j0 + jp + 1];
                    gz0 = gir[Hd + j0 + jp];   gz1 = gir[Hd + j0 + jp + 1];
                    gn0 = gir[2*Hd + j0 + jp]; gn1 = gir[2*Hd + j0 + jp + 1];
                }
                if (wave == 0) {
                    const unsigned tgt = (unsigned)(t + 1);
                    while (!__all(__hip_atomic_load(&cnt[lane], __ATOMIC_RELAXED,
                                                    __HIP_MEMORY_SCOPE_AGENT) >= tgt))
                        __builtin_amdgcn_s_sleep(2);
                }
                __syncthreads();
            }
        }
        return;
    }

    // ================= logits-GEMM pool role =================
    {
        u16* As = (u16*)SM;                 // [128][128] u16, XOR-swizzled, 32KB
        u16* Bs = (u16*)(SM + 32768);       // [2 tiles][4 kc][128*32] u16, 64KB
        const int g     = blockIdx.x - NB;  // 0..191
        const int tile0 = g;
        const int tile1 = g + NPOOL;
        const bool two  = (tile1 < NTILE);

        const int wm = (wave & 1) << 6;
        const int wn = (wave >> 1) << 6;
        const int c0 = wave * 2, c1 = wave * 2 + 1;
        const int cr = lane >> 2;
        const int kg = lane & 3;
        // w_out source rows for B staging (per sub-chunk add k offset)
        const u16* gB0a = w_outb + (size_t)(tile0*128 + c0*16 + cr) * Hd + kg*8;
        const u16* gB1a = w_outb + (size_t)(tile0*128 + c1*16 + cr) * Hd + kg*8;
        const u16* gB0b = w_outb + (size_t)((two ? tile1 : tile0)*128 + c0*16 + cr) * Hd + kg*8;
        const u16* gB1b = w_outb + (size_t)((two ? tile1 : tile0)*128 + c1*16 + cr) * Hd + kg*8;

        const int arow  = tid >> 1;         // 0..127 (A staging row)
        const int ahalf = tid & 1;          // which 128B half of the 256B row chunk

        for (int G = 0; G < 16; ++G) {
            // wait: steps 4G..4G+3 complete on all 64 GRU blocks
            if (wave == 0) {
                const unsigned tgt = (unsigned)(4 * (G + 1));
                while (!__all(__hip_atomic_load(&cnt[lane], __ATOMIC_RELAXED,
                                                __HIP_MEMORY_SCOPE_AGENT) >= tgt))
                    __builtin_amdgcn_s_sleep(8);
            }
            __syncthreads();

            f32x4 acc0[4][4], acc1[4][4];
#pragma unroll
            for (int i = 0; i < 4; ++i)
#pragma unroll
                for (int j = 0; j < 4; ++j) {
                    f32x4 z = {0.f,0.f,0.f,0.f};
                    acc0[i][j] = z; acc1[i][j] = z;
                }

            const size_t arow0 = (size_t)G * 128;   // hsb row base of this group

            for (int s = 0; s < 8; ++s) {           // super-chunks of K=128
                const int k0 = s * 128;
                // A: 8 sc loads of 16B per thread (stale-L2-proof)
                const u16* asrc = hsb + (arow0 + arow) * Hd + k0 + ahalf * 64;
                u32x4 ar[8];
#pragma unroll
                for (int j = 0; j < 8; ++j)
                    ar[j] = gload_b128_sc(asrc + j*8);
                // B: async global->LDS for 4 sub-chunks x (1 or 2) tiles
#pragma unroll
                for (int kc = 0; kc < 4; ++kc) {
                    const int kk = k0 + kc*32;
                    u16* base0 = &Bs[(0*4 + kc) * 4096];
                    async_ld16(gB0a + kk, base0 + c0*512 + lane*8);
                    async_ld16(gB1a + kk, base0 + c1*512 + lane*8);
                    if (two) {
                        u16* base1 = &Bs[(1*4 + kc) * 4096];
                        async_ld16(gB0b + kk, base1 + c0*512 + lane*8);
                        async_ld16(gB1b + kk, base1 + c1*512 + lane*8);
                    }
                }
                asm volatile("s_waitcnt vmcnt(0)" ::: "memory");
                // A -> LDS, XOR-swizzled (bank-spread for the frag reads)
#pragma unroll
                for (int j = 0; j < 8; ++j) {
                    const int ob = (ahalf*128 + j*16) ^ ((arow & 7) << 4);
                    *(u32x4*)((unsigned char*)As + arow*256 + ob) = ar[j];
                }
                __syncthreads();

#pragma unroll
                for (int kc = 0; kc < 4; ++kc) {
                    bf16x8 af[4];
#pragma unroll
                    for (int i = 0; i < 4; ++i) {
                        const int row = wm + i*16 + l16;
                        const int ob  = (kc*64 + q*16) ^ ((row & 7) << 4);
                        af[i] = *(const bf16x8*)((const unsigned char*)As + row*256 + ob);
                    }
                    bf16x8 b0[4];
#pragma unroll
                    for (int j = 0; j < 4; ++j)
                        b0[j] = *(const bf16x8*)&Bs[(0*4 + kc)*4096 + (wn + j*16 + l16)*32 + q*8];
#pragma unroll
                    for (int i = 0; i < 4; ++i)
#pragma unroll
                        for (int j = 0; j < 4; ++j)
                            acc0[i][j] = __builtin_amdgcn_mfma_f32_16x16x32_bf16(af[i], b0[j], acc0[i][j], 0, 0, 0);
                    if (two) {
                        bf16x8 b1[4];
#pragma unroll
                        for (int j = 0; j < 4; ++j)
                            b1[j] = *(const bf16x8*)&Bs[(1*4 + kc)*4096 + (wn + j*16 + l16)*32 + q*8];
#pragma unroll
                        for (int i = 0; i < 4; ++i)
#pragma unroll
                            for (int j = 0; j < 4; ++j)
                                acc1[i][j] = __builtin_amdgcn_mfma_f32_16x16x32_bf16(af[i], b1[j], acc1[i][j], 0, 0, 0);
                    }
                }
                __syncthreads();
            }

            // epilogue: out[((b<<6)+t)*V + n] = acc + bias  (NON-TEMPORAL)
#pragma unroll
            for (int i = 0; i < 4; ++i) {
                const int lmbase = wm + i*16 + q*4;
#pragma unroll
                for (int j = 0; j < 4; ++j) {
                    const int n0 = tile0*128 + wn + j*16 + l16;
                    const float bv0 = b_out[n0];
#pragma unroll
                    for (int r = 0; r < 4; ++r) {
                        const int gr = (int)(G*128) + lmbase + r;   // hsb row = t*32+b
                        const int tt = gr >> 5, bb = gr & 31;
                        gstore_f32_nt(&out[(size_t)((bb << 6) + tt) * Vd + n0],
                                      acc0[i][j][r] + bv0);
                    }
                }
            }
            if (two) {
#pragma unroll
                for (int i = 0; i < 4; ++i) {
                    const int lmbase = wm + i*16 + q*4;
#pragma unroll
                    for (int j = 0; j < 4; ++j) {
                        const int n1 = tile1*128 + wn + j*16 + l16;
                        const float bv1 = b_out[n1];
#pragma unroll
                        for (int r = 0; r < 4; ++r) {
                            const int gr = (int)(G*128) + lmbase + r;
                            const int tt = gr >> 5, bb = gr & 31;
                            gstore_f32_nt(&out[(size_t)((bb << 6) + tt) * Vd + n1],
                                          acc1[i][j][r] + bv1);
                        }
                    }
                }
            }
        }
    }
}

// ---------------- in-place log-softmax over rows of 32000 ----------------
__global__ __launch_bounds__(256)
void k_logsoftmax(float* __restrict__ out) {
    float* row = out + (size_t)blockIdx.x * Vd;
    const int tid = threadIdx.x;
    float m = -1e30f, s = 0.f;
    for (int i = tid * 4; i + 3 < Vd; i += 1024) {
        float4 f = *(const float4*)(row + i);
        float lm = fmaxf(fmaxf(f.x, f.y), fmaxf(f.z, f.w));
        if (lm > m) { s *= __expf(m - lm); m = lm; }
        s += __expf(f.x - m) + __expf(f.y - m) + __expf(f.z - m) + __expf(f.w - m);
    }
    for (int off = 32; off > 0; off >>= 1) {
        float mo = __shfl_down(m, off, 64);
        float so = __shfl_down(s, off, 64);
        float M = fmaxf(m, mo);
        s = s * __expf(m - M) + so * __expf(mo - M);
        m = M;
    }
    __shared__ float sm[4], ss[4];
    const int wave = tid >> 6, lane = tid & 63;
    if (lane == 0) { sm[wave] = m; ss[wave] = s; }
    __syncthreads();
    const float M = fmaxf(fmaxf(sm[0], sm[1]), fmaxf(sm[2], sm[3]));
    const float S = ss[0]*__expf(sm[0]-M) + ss[1]*__expf(sm[1]-M)
                  + ss[2]*__expf(sm[2]-M) + ss[3]*__expf(sm[3]-M);
    const float lz = M + logf(S);
    for (int i = tid * 4; i + 3 < Vd; i += 1024) {
        float4 f = *(const float4*)(row + i);
        f.x -= lz; f.y -= lz; f.z -= lz; f.w -= lz;
        *(float4*)(row + i) = f;
    }
}

extern "C" void kernel_launch(void* const* d_in, const int* in_sizes, int n_in,
                              void* d_out, int out_size, void* d_ws, size_t ws_size,
                              hipStream_t stream) {
    const float* enc_h = (const float*)d_in[1];   // [1,B,H]
    const int*   tgt   = (const int*)d_in[2];     // [B,T]
    const float* emb   = (const float*)d_in[3];   // [V,H]
    const float* w_ih  = (const float*)d_in[4];   // [3H,H]
    const float* w_hh  = (const float*)d_in[5];   // [3H,H]
    const float* b_ih  = (const float*)d_in[6];   // [3H]
    const float* b_hh  = (const float*)d_in[7];   // [3H]
    const float* w_out = (const float*)d_in[8];   // [V,H]
    const float* b_out = (const float*)d_in[9];   // [V]
    float* out = (float*)d_out;

    char* ws = (char*)d_ws;
    size_t off = 0;
    auto alloc = [&](size_t bytes) { void* p = ws + off; off += (bytes + 255) & ~(size_t)255; return p; };
    u16*   w_outb = (u16*)  alloc((size_t)Vd * Hd * 2);     // 65.5 MB
    u16*   w_ihb  = (u16*)  alloc((size_t)G3H * Hd * 2);    // 6.3 MB
    u16*   w_hhb  = (u16*)  alloc((size_t)G3H * Hd * 2);    // 6.3 MB
    u16*   Xb     = (u16*)  alloc((size_t)TB * Hd * 2);     // 4.2 MB
    u16*   hsb    = (u16*)  alloc((size_t)TB * Hd * 2);     // 4.2 MB
    float* gi     = (float*)alloc((size_t)TB * G3H * 4);    // 25.2 MB
    u16*   hb0    = (u16*)  alloc((size_t)Bd * Hd * 2);
    u16*   hb1    = (u16*)  alloc((size_t)Bd * Hd * 2);
    unsigned int* cnt = (unsigned int*) alloc(256);         // 64 per-block flags
    (void)ws_size; (void)in_sizes; (void)n_in; (void)out_size;

    // weight conversions + embedding gather (parallel, no dependencies)
    k_conv_bf16<<<(Vd*Hd/4 + 255)/256, 256, 0, stream>>>(w_out, w_outb, Vd*Hd/4);
    k_conv_bf16<<<(G3H*Hd/4 + 255)/256, 256, 0, stream>>>(w_ih, w_ihb, G3H*Hd/4);
    k_conv_bf16<<<(G3H*Hd/4 + 255)/256, 256, 0, stream>>>(w_hh, w_hhb, G3H*Hd/4);
    k_embed<<<TB, 256, 0, stream>>>(emb, tgt, Xb);
    k_init_h<<<32, 256, 0, stream>>>(enc_h, hb0, cnt);

    // gi = relu(emb[tok]) @ w_ih^T + b_ih  for all T*B rows
    k_gemm128<0,0><<<dim3(G3H/128, TB/128), 256, 0, stream>>>(Xb, w_ihb, b_ih, gi, G3H, Hd);

    // fused: GRU recurrence (blocks 0-63) + flag-gated logits GEMM (64-255)
    k_gru_logits<<<NB + NPOOL, 256, 0, stream>>>(gi, enc_h, w_hhb, b_hh, hb0, hb1,
                                                 hsb, out + BTV, cnt,
                                                 w_outb, b_out, out);

    // in-place log-softmax per (b,t) row
    k_logsoftmax<<<TB, 256, 0, stream>>>(out);
}

// Round 6
// 1003.985 us; speedup vs baseline: 1.1946x; 1.1946x over previous
//
#include <hip/hip_runtime.h>
#include <stdint.h>

#define Hd 1024
#define Bd 32
#define Td 64
#define Vd 32000
#define TB (Td*Bd)            // 2048
#define G3H 3072
#define NB 64                 // GRU blocks (block 0..63)
#define NPOOL 192             // logits-GEMM pool blocks (block 64..255)
#define JC 16                 // h-columns per GRU block
#define NTILE 250             // 32000 / 128
#define NITEMS 2000           // 8 row-groups x 250 n-tiles
static const size_t BTV = (size_t)Bd * Td * Vd;   // 65,536,000

typedef unsigned short u16;
typedef __attribute__((ext_vector_type(8))) short bf16x8;
typedef __attribute__((ext_vector_type(4))) float f32x4;
typedef __attribute__((ext_vector_type(4))) unsigned int u32x4;

typedef __attribute__((address_space(3))) void lds_void;
typedef __attribute__((address_space(1))) const void gbl_void;

__device__ __forceinline__ void async_ld16(const void* g, void* l) {
    __builtin_amdgcn_global_load_lds((gbl_void*)g, (lds_void*)l, 16, 0, 0);
}

__device__ __forceinline__ u16 f2bf(float f) {
    union { float f; uint32_t u; } v; v.f = f;
    uint32_t u = v.u;
    return (u16)((u + 0x7fffu + ((u >> 16) & 1u)) >> 16);
}

// PROVEN primitives: sc0 sc1 cache-bypassing load/store, coherent for all
// blocks at the coherence point (LLC-served per round-1 FETCH_SIZE evidence).
__device__ __forceinline__ u32x4 gload_b128_sc(const u16* p) {
    u32x4 r;
    asm volatile("global_load_dwordx4 %0, %1, off sc0 sc1"
                 : "=v"(r) : "v"(p) : "memory");
    return r;
}
__device__ __forceinline__ void gstore_b32_sc(u16* p, unsigned int v) {
    asm volatile("global_store_dword %0, %1, off sc0 sc1"
                 :: "v"(p), "v"(v) : "memory");
}
__device__ __forceinline__ void gstore_u32_sc(unsigned int* p, unsigned int v) {
    asm volatile("global_store_dword %0, %1, off sc0 sc1"
                 :: "v"(p), "v"(v) : "memory");
}

__device__ __forceinline__ float fsigmoid(float x) {
    return __builtin_amdgcn_rcpf(1.f + __expf(-x));
}
__device__ __forceinline__ float ftanh(float x) {
    return 1.f - 2.f * __builtin_amdgcn_rcpf(1.f + __expf(2.f * x));
}

// ---------------- fp32 -> bf16 convert ----------------
__global__ void k_conv_bf16(const float* __restrict__ src, u16* __restrict__ dst, int n4) {
    int i = blockIdx.x * blockDim.x + threadIdx.x;
    if (i >= n4) return;
    float4 f = ((const float4*)src)[i];
    ushort4 o;
    o.x = f2bf(f.x); o.y = f2bf(f.y); o.z = f2bf(f.z); o.w = f2bf(f.w);
    ((ushort4*)dst)[i] = o;
}

// ---------------- embedding gather + relu + bf16 ----------------
__global__ void k_embed(const float* __restrict__ emb, const int* __restrict__ tgt,
                        u16* __restrict__ Xb) {
    int r = blockIdx.x;            // r = t*32 + b
    int t = r >> 5, b = r & 31;
    int tok = (t == 0) ? 1 : tgt[b * Td + (t - 1)];
    const float4* srow = (const float4*)(emb + (size_t)tok * Hd);
    int k = threadIdx.x;
    float4 f = srow[k];
    ushort4 o;
    o.x = f2bf(fmaxf(f.x, 0.f)); o.y = f2bf(fmaxf(f.y, 0.f));
    o.z = f2bf(fmaxf(f.z, 0.f)); o.w = f2bf(fmaxf(f.w, 0.f));
    ((ushort4*)(Xb + (size_t)r * Hd))[k] = o;
}

// ---------------- h init: bf16 copy + flag/queue zero ----------------
__global__ void k_init_h(const float* __restrict__ eh, u16* __restrict__ hb,
                         unsigned int* __restrict__ cnt) {
    if (blockIdx.x == 0 && threadIdx.x < 128) cnt[threadIdx.x] = 0u;  // 64 flags + queue
    int i = blockIdx.x * blockDim.x + threadIdx.x;   // 8192 float4s
    float4 f = ((const float4*)eh)[i];
    ushort4 o;
    o.x = f2bf(f.x); o.y = f2bf(f.y); o.z = f2bf(f.z); o.w = f2bf(f.w);
    ((ushort4*)hb)[i] = o;
}

// ---------------- 128x128 bf16 MFMA GEMM: C = A @ Bm^T + bias (gi only) ---
template<int MODE, int SWAP>
__global__ __launch_bounds__(256, 2)
void k_gemm128(const u16* __restrict__ A, const u16* __restrict__ Bm,
               const float* __restrict__ bias, float* __restrict__ C,
               int N, int K)
{
    __shared__ alignas(16) u16 As[128 * 32];
    __shared__ alignas(16) u16 Bs[128 * 32];
    const int tid  = threadIdx.x;
    const int wave = tid >> 6;
    const int lane = tid & 63;
    const int l16  = lane & 15;
    const int q    = lane >> 4;
    const int wm   = (wave & 1) << 6;
    const int wn   = (wave >> 1) << 6;
    const int tm   = (SWAP ? blockIdx.x : blockIdx.y) << 7;
    const int tn   = (SWAP ? blockIdx.y : blockIdx.x) << 7;

    f32x4 acc[4][4];
#pragma unroll
    for (int i = 0; i < 4; ++i)
#pragma unroll
        for (int j = 0; j < 4; ++j) { f32x4 z = {0.f,0.f,0.f,0.f}; acc[i][j] = z; }

    const int c0 = wave * 2, c1 = wave * 2 + 1;
    const int cr = lane >> 2;
    const int kg = lane & 3;
    const u16* gA0 = A + (size_t)(tm + c0*16 + cr) * K + kg*8;
    const u16* gA1 = A + (size_t)(tm + c1*16 + cr) * K + kg*8;
    const u16* gB0 = Bm + (size_t)(tn + c0*16 + cr) * K + kg*8;
    const u16* gB1 = Bm + (size_t)(tn + c1*16 + cr) * K + kg*8;
    u16* lA0 = &As[c0*512 + lane*8];
    u16* lA1 = &As[c1*512 + lane*8];
    u16* lB0 = &Bs[c0*512 + lane*8];
    u16* lB1 = &Bs[c1*512 + lane*8];

    for (int k0 = 0; k0 < K; k0 += 32) {
        async_ld16(gA0 + k0, lA0);
        async_ld16(gA1 + k0, lA1);
        async_ld16(gB0 + k0, lB0);
        async_ld16(gB1 + k0, lB1);
        __syncthreads();
        bf16x8 af[4], bfr[4];
#pragma unroll
        for (int i = 0; i < 4; ++i)
            af[i] = *(const bf16x8*)&As[(wm + i*16 + l16) * 32 + q*8];
#pragma unroll
        for (int j = 0; j < 4; ++j)
            bfr[j] = *(const bf16x8*)&Bs[(wn + j*16 + l16) * 32 + q*8];
#pragma unroll
        for (int i = 0; i < 4; ++i)
#pragma unroll
            for (int j = 0; j < 4; ++j)
                acc[i][j] = __builtin_amdgcn_mfma_f32_16x16x32_bf16(af[i], bfr[j], acc[i][j], 0, 0, 0);
        __syncthreads();
    }

#pragma unroll
    for (int i = 0; i < 4; ++i) {
        const int mbase = tm + wm + i*16 + q*4;
#pragma unroll
        for (int j = 0; j < 4; ++j) {
            const int n = tn + wn + j*16 + l16;
            const float bv = bias[n];
#pragma unroll
            for (int r = 0; r < 4; ++r) {
                const int m = mbase + r;
                const float v = acc[i][j][r] + bv;
                if (MODE == 0) {
                    C[(size_t)m * N + n] = v;
                } else {
                    const int tt = m >> 5, bb = m & 31;
                    C[(size_t)((bb << 6) + tt) * Vd + n] = v;
                }
            }
        }
    }
}

// ---------------- fused persistent: GRU recurrence + streamed logits GEMM --
// 256 blocks x 256 threads, 1 block/CU.
// Blocks 0..63:  GRU (proven round-3 code; flags incl. t=63 -> 64).
// Blocks 64..255: work-queue pool. Item w: G8=w/250 (8-step row group,
//   256 hsb rows), tile=w%250 (128 w_out cols). Gated on flags>=8(G8+1).
//   A: direct global->reg sc loads in fragment layout (no LDS).
//   B: LDS double-buffer via global_load_lds, counted vmcnt(24), raw
//   s_barrier (NOT __syncthreads: that drains vmcnt0 and kills the pipe),
//   source-pre-swizzled k-slots (^= row&3) to cut bank conflicts.
__global__ __launch_bounds__(256, 1)
void k_gru_logits(const float* __restrict__ gi,
                  const float* __restrict__ enc_h,
                  const u16* __restrict__ w_hhb,
                  const float* __restrict__ b_hh,
                  u16* __restrict__ hbA, u16* __restrict__ hbB,
                  u16* __restrict__ hsb, float* __restrict__ hlast,
                  unsigned int* __restrict__ cnt,
                  const u16* __restrict__ w_outb,
                  const float* __restrict__ b_out,
                  float* __restrict__ out)
{
    __shared__ alignas(16) unsigned char SM[111360];
    const int tid  = threadIdx.x;
    const int wave = tid >> 6, lane = tid & 63;
    const int l16  = lane & 15, q = lane >> 4;

    if (blockIdx.x < NB) {
        // ================= GRU role (proven) =================
        u16* Ws = (u16*)SM;                                  // 48*1024 u16 = 96KB
        typedef float ghs_t[3][32][17];
        ghs_t* ghs = (ghs_t*)(SM + 98304);                   // [2][3][32][17] f32
        const int j0 = blockIdx.x * JC;

        for (int idx = tid; idx < 48 * 128; idx += 256) {
            int gr = idx >> 7;
            int c  = idx & 127;
            const u16* src = w_hhb + (size_t)((gr >> 4) * Hd + j0 + (gr & 15)) * Hd + c * 8;
            *(bf16x8*)&Ws[(size_t)(c * 48 + gr) * 8] = *(const bf16x8*)src;
        }

        const int b  = tid >> 3;
        const int jp = (tid & 7) * 2;
        float h0 = enc_h[b * Hd + j0 + jp];
        float h1 = enc_h[b * Hd + j0 + jp + 1];
        const float br0 = b_hh[j0 + jp],           br1 = b_hh[j0 + jp + 1];
        const float bz0 = b_hh[Hd + j0 + jp],      bz1 = b_hh[Hd + j0 + jp + 1];
        const float bn0 = b_hh[2*Hd + j0 + jp],    bn1 = b_hh[2*Hd + j0 + jp + 1];

        const int mh = wave & 1, kh = wave >> 1;

        float gr0, gr1, gz0, gz1, gn0, gn1;
        {
            const float* gir = gi + (size_t)b * G3H;
            gr0 = gir[j0 + jp];        gr1 = gir[j0 + jp + 1];
            gz0 = gir[Hd + j0 + jp];   gz1 = gir[Hd + j0 + jp + 1];
            gn0 = gir[2*Hd + j0 + jp]; gn1 = gir[2*Hd + j0 + jp + 1];
        }

        __syncthreads();   // Ws ready

        for (int t = 0; t < Td; ++t) {
            const u16* hb_in  = (t & 1) ? hbB : hbA;
            u16*       hb_out = (t & 1) ? hbA : hbB;
            const int row = t * 32 + b;

            const u16* ap = hb_in + (size_t)(mh*16 + l16) * Hd + kh*512 + q*8;
            u32x4 areg[16];
#pragma unroll
            for (int it = 0; it < 16; ++it)
                areg[it] = gload_b128_sc(ap + it*32);

            asm volatile("s_waitcnt vmcnt(0)" ::: "memory");

            f32x4 acc0 = {0.f,0.f,0.f,0.f}, acc1 = acc0, acc2 = acc0;
#pragma unroll
            for (int it = 0; it < 16; ++it) {
                bf16x8 a = __builtin_bit_cast(bf16x8, areg[it]);
                const int kgrp = kh*64 + it*4 + q;
                const u16* wp = &Ws[(size_t)(kgrp * 48 + l16) * 8];
                bf16x8 w0 = *(const bf16x8*)(wp);
                bf16x8 w1 = *(const bf16x8*)(wp + 16*8);
                bf16x8 w2 = *(const bf16x8*)(wp + 32*8);
                acc0 = __builtin_amdgcn_mfma_f32_16x16x32_bf16(a, w0, acc0, 0, 0, 0);
                acc1 = __builtin_amdgcn_mfma_f32_16x16x32_bf16(a, w1, acc1, 0, 0, 0);
                acc2 = __builtin_amdgcn_mfma_f32_16x16x32_bf16(a, w2, acc2, 0, 0, 0);
            }
#pragma unroll
            for (int r = 0; r < 4; ++r) {
                const int bb = mh*16 + q*4 + r;
                ghs[kh][0][bb][l16] = acc0[r];
                ghs[kh][1][bb][l16] = acc1[r];
                ghs[kh][2][bb][l16] = acc2[r];
            }
            __syncthreads();

            {
                const float hr0 = ghs[0][0][b][jp]   + ghs[1][0][b][jp]   + br0;
                const float hr1 = ghs[0][0][b][jp+1] + ghs[1][0][b][jp+1] + br1;
                const float hz0 = ghs[0][1][b][jp]   + ghs[1][1][b][jp]   + bz0;
                const float hz1 = ghs[0][1][b][jp+1] + ghs[1][1][b][jp+1] + bz1;
                const float hn0 = ghs[0][2][b][jp]   + ghs[1][2][b][jp]   + bn0;
                const float hn1 = ghs[0][2][b][jp+1] + ghs[1][2][b][jp+1] + bn1;
                const float rg0 = fsigmoid(gr0 + hr0);
                const float rg1 = fsigmoid(gr1 + hr1);
                const float zg0 = fsigmoid(gz0 + hz0);
                const float zg1 = fsigmoid(gz1 + hz1);
                const float ng0 = ftanh(gn0 + rg0 * hn0);
                const float ng1 = ftanh(gn1 + rg1 * hn1);
                h0 = (1.f - zg0) * ng0 + zg0 * h0;
                h1 = (1.f - zg1) * ng1 + zg1 * h1;
                ushort2 pv; pv.x = f2bf(h0); pv.y = f2bf(h1);
                const unsigned int pw = (unsigned int)pv.x | ((unsigned int)pv.y << 16);
                gstore_b32_sc(&hb_out[b * Hd + j0 + jp], pw);
                gstore_b32_sc(&hsb[(size_t)row * Hd + j0 + jp], pw);   // sc: pool-visible
                if (t == Td - 1) {
                    hlast[b * Hd + j0 + jp]     = h0;
                    hlast[b * Hd + j0 + jp + 1] = h1;
                }
            }

            __syncthreads();   // drains sc stores (h + hsb) to the LLC
            if (tid == 0)
                gstore_u32_sc(&cnt[blockIdx.x], (unsigned)(t + 1));  // incl. t=63 -> 64

            if (t < Td - 1) {
                {
                    const float* gir = gi + (size_t)((t + 1) * 32 + b) * G3H;
                    gr0 = gir[j0 + jp];        gr1 = gir[j0 + jp + 1];
                    gz0 = gir[Hd + j0 + jp];   gz1 = gir[Hd + j0 + jp + 1];
                    gn0 = gir[2*Hd + j0 + jp]; gn1 = gir[2*Hd + j0 + jp + 1];
                }
                if (wave == 0) {
                    const unsigned tgt = (unsigned)(t + 1);
                    while (!__all(__hip_atomic_load(&cnt[lane], __ATOMIC_RELAXED,
                                                    __HIP_MEMORY_SCOPE_AGENT) >= tgt))
                        __builtin_amdgcn_s_sleep(2);
                }
                __syncthreads();
            }
        }
        return;
    }

    // ================= logits-GEMM pool role (work queue) =================
    {
        u16* Bs = (u16*)SM;                               // [2][4][128][32] u16 = 64KB
        volatile unsigned* qw = (volatile unsigned*)(SM + 65536);
        const int cr = lane >> 2;                         // B staging row within 16
        const int kg = lane & 3;                          // B staging dest k-slot
        const int c0 = wave * 2, c1 = wave * 2 + 1;
        const int kgs = (kg ^ (cr & 3)) * 8;              // pre-swizzled source k offset

        for (;;) {
            if (tid == 0) *qw = atomicAdd(&cnt[64], 1u);  // grab next work item
            __syncthreads();
            const unsigned w = *qw;
            __syncthreads();
            if (w >= (unsigned)NITEMS) break;
            const int G8   = (int)(w / (unsigned)NTILE);
            const int tile = (int)(w % (unsigned)NTILE);

            // gate: hsb rows [G8*256, G8*256+256) complete on all GRU blocks
            if (wave == 0) {
                const unsigned tgt = (unsigned)(8 * (G8 + 1));
                while (!__all(__hip_atomic_load(&cnt[lane], __ATOMIC_RELAXED,
                                                __HIP_MEMORY_SCOPE_AGENT) >= tgt))
                    __builtin_amdgcn_s_sleep(8);
            }
            __syncthreads();

            const int rowbase = G8 * 256 + wave * 64;     // this wave's 64 A-rows
            const u16* Ab  = hsb + (size_t)(rowbase + l16) * Hd + q * 8;
            const u16* Bg0 = w_outb + (size_t)(tile*128 + c0*16 + cr) * Hd + kgs;
            const u16* Bg1 = w_outb + (size_t)(tile*128 + c1*16 + cr) * Hd + kgs;
            u16* Bd0 = Bs + (c0*16 + cr)*32 + kg*8;       // + buf*16384 + kc*4096
            u16* Bd1 = Bs + (c1*16 + cr)*32 + kg*8;

            f32x4 acc[4][8];
#pragma unroll
            for (int i = 0; i < 4; ++i)
#pragma unroll
                for (int j = 0; j < 8; ++j) { f32x4 z = {0.f,0.f,0.f,0.f}; acc[i][j] = z; }

            u32x4 areg[2][4][4];
            // prologue: issue chunk 0 (8 B-async + 16 A loads = 24 ops)
#pragma unroll
            for (int kc = 0; kc < 4; ++kc) {
                async_ld16(Bg0 + kc*32, Bd0 + kc*4096);
                async_ld16(Bg1 + kc*32, Bd1 + kc*4096);
            }
#pragma unroll
            for (int i = 0; i < 4; ++i)
#pragma unroll
                for (int kc = 0; kc < 4; ++kc)
                    areg[0][i][kc] = gload_b128_sc(Ab + (size_t)i*16*Hd + kc*32);

#pragma unroll
            for (int s = 0; s < 8; ++s) {
                const int cur = s & 1, nxt = cur ^ 1;
                if (s < 7) {
                    const int k0 = (s + 1) * 128;
#pragma unroll
                    for (int kc = 0; kc < 4; ++kc) {
                        async_ld16(Bg0 + k0 + kc*32, Bd0 + nxt*16384 + kc*4096);
                        async_ld16(Bg1 + k0 + kc*32, Bd1 + nxt*16384 + kc*4096);
                    }
#pragma unroll
                    for (int i = 0; i < 4; ++i)
#pragma unroll
                        for (int kc = 0; kc < 4; ++kc)
                            areg[nxt][i][kc] = gload_b128_sc(Ab + (size_t)i*16*Hd + k0 + kc*32);
                    asm volatile("s_waitcnt vmcnt(24)" ::: "memory");   // chunk s resident
                } else {
                    asm volatile("s_waitcnt vmcnt(0)" ::: "memory");
                }
                __builtin_amdgcn_sched_barrier(0);        // rule 18: pin MFMA after wait
                __builtin_amdgcn_s_barrier();             // raw: no vmcnt(0) drain
#pragma unroll
                for (int kc = 0; kc < 4; ++kc) {
#pragma unroll
                    for (int j = 0; j < 8; ++j) {
                        const int n = j*16 + l16;
                        const bf16x8 bj = *(const bf16x8*)
                            &Bs[cur*16384 + kc*4096 + n*32 + (q ^ (n & 3))*8];
#pragma unroll
                        for (int i = 0; i < 4; ++i)
                            acc[i][j] = __builtin_amdgcn_mfma_f32_16x16x32_bf16(
                                __builtin_bit_cast(bf16x8, areg[cur][i][kc]), bj,
                                acc[i][j], 0, 0, 0);
                    }
                }
                __builtin_amdgcn_s_barrier();             // buffer reuse fence
            }

            // epilogue: out[((b<<6)+t)*V + n] = acc + bias
#pragma unroll
            for (int j = 0; j < 8; ++j) {
                const int n = tile*128 + j*16 + l16;
                const float bv = b_out[n];
#pragma unroll
                for (int i = 0; i < 4; ++i) {
                    const int mbase = rowbase + i*16 + q*4;
#pragma unroll
                    for (int r = 0; r < 4; ++r) {
                        const int m = mbase + r;              // hsb row = t*32+b
                        const int tt = m >> 5, bb = m & 31;
                        out[(size_t)((bb << 6) + tt) * Vd + n] = acc[i][j][r] + bv;
                    }
                }
            }
        }
    }
}

// ---------------- in-place log-softmax over rows of 32000 ----------------
__global__ __launch_bounds__(256)
void k_logsoftmax(float* __restrict__ out) {
    float* row = out + (size_t)blockIdx.x * Vd;
    const int tid = threadIdx.x;
    float m = -1e30f, s = 0.f;
    for (int i = tid * 4; i + 3 < Vd; i += 1024) {
        float4 f = *(const float4*)(row + i);
        float lm = fmaxf(fmaxf(f.x, f.y), fmaxf(f.z, f.w));
        if (lm > m) { s *= __expf(m - lm); m = lm; }
        s += __expf(f.x - m) + __expf(f.y - m) + __expf(f.z - m) + __expf(f.w - m);
    }
    for (int off = 32; off > 0; off >>= 1) {
        float mo = __shfl_down(m, off, 64);
        float so = __shfl_down(s, off, 64);
        float M = fmaxf(m, mo);
        s = s * __expf(m - M) + so * __expf(mo - M);
        m = M;
    }
    __shared__ float sm[4], ss[4];
    const int wave = tid >> 6, lane = tid & 63;
    if (lane == 0) { sm[wave] = m; ss[wave] = s; }
    __syncthreads();
    const float M = fmaxf(fmaxf(sm[0], sm[1]), fmaxf(sm[2], sm[3]));
    const float S = ss[0]*__expf(sm[0]-M) + ss[1]*__expf(sm[1]-M)
                  + ss[2]*__expf(sm[2]-M) + ss[3]*__expf(sm[3]-M);
    const float lz = M + logf(S);
    for (int i = tid * 4; i + 3 < Vd; i += 1024) {
        float4 f = *(const float4*)(row + i);
        f.x -= lz; f.y -= lz; f.z -= lz; f.w -= lz;
        *(float4*)(row + i) = f;
    }
}

extern "C" void kernel_launch(void* const* d_in, const int* in_sizes, int n_in,
                              void* d_out, int out_size, void* d_ws, size_t ws_size,
                              hipStream_t stream) {
    const float* enc_h = (const float*)d_in[1];   // [1,B,H]
    const int*   tgt   = (const int*)d_in[2];     // [B,T]
    const float* emb   = (const float*)d_in[3];   // [V,H]
    const float* w_ih  = (const float*)d_in[4];   // [3H,H]
    const float* w_hh  = (const float*)d_in[5];   // [3H,H]
    const float* b_ih  = (const float*)d_in[6];   // [3H]
    const float* b_hh  = (const float*)d_in[7];   // [3H]
    const float* w_out = (const float*)d_in[8];   // [V,H]
    const float* b_out = (const float*)d_in[9];   // [V]
    float* out = (float*)d_out;

    char* ws = (char*)d_ws;
    size_t off = 0;
    auto alloc = [&](size_t bytes) { void* p = ws + off; off += (bytes + 255) & ~(size_t)255; return p; };
    u16*   w_outb = (u16*)  alloc((size_t)Vd * Hd * 2);     // 65.5 MB
    u16*   w_ihb  = (u16*)  alloc((size_t)G3H * Hd * 2);    // 6.3 MB
    u16*   w_hhb  = (u16*)  alloc((size_t)G3H * Hd * 2);    // 6.3 MB
    u16*   Xb     = (u16*)  alloc((size_t)TB * Hd * 2);     // 4.2 MB
    u16*   hsb    = (u16*)  alloc((size_t)TB * Hd * 2);     // 4.2 MB
    float* gi     = (float*)alloc((size_t)TB * G3H * 4);    // 25.2 MB
    u16*   hb0    = (u16*)  alloc((size_t)Bd * Hd * 2);
    u16*   hb1    = (u16*)  alloc((size_t)Bd * Hd * 2);
    unsigned int* cnt = (unsigned int*) alloc(512);         // 64 flags + queue ctr
    (void)ws_size; (void)in_sizes; (void)n_in; (void)out_size;

    // weight conversions + embedding gather (parallel, no dependencies)
    k_conv_bf16<<<(Vd*Hd/4 + 255)/256, 256, 0, stream>>>(w_out, w_outb, Vd*Hd/4);
    k_conv_bf16<<<(G3H*Hd/4 + 255)/256, 256, 0, stream>>>(w_ih, w_ihb, G3H*Hd/4);
    k_conv_bf16<<<(G3H*Hd/4 + 255)/256, 256, 0, stream>>>(w_hh, w_hhb, G3H*Hd/4);
    k_embed<<<TB, 256, 0, stream>>>(emb, tgt, Xb);
    k_init_h<<<32, 256, 0, stream>>>(enc_h, hb0, cnt);

    // gi = relu(emb[tok]) @ w_ih^T + b_ih  for all T*B rows
    k_gemm128<0,0><<<dim3(G3H/128, TB/128), 256, 0, stream>>>(Xb, w_ihb, b_ih, gi, G3H, Hd);

    // fused: GRU recurrence (blocks 0-63) + queue-driven logits GEMM (64-255)
    k_gru_logits<<<NB + NPOOL, 256, 0, stream>>>(gi, enc_h, w_hhb, b_hh, hb0, hb1,
                                                 hsb, out + BTV, cnt,
                                                 w_outb, b_out, out);

    // in-place log-softmax per (b,t) row
    k_logsoftmax<<<TB, 256, 0, stream>>>(out);
}